// Round 4
// baseline (670.554 us; speedup 1.0000x reference)
//
#include <hip/hip_runtime.h>
#include <hip/hip_bf16.h>

typedef __attribute__((ext_vector_type(8))) short s16x8;
typedef __attribute__((ext_vector_type(4))) float f32x4;
typedef unsigned short u16;
typedef unsigned int u32;

__device__ __forceinline__ u16 f2b(float f) {
    u32 u = __float_as_uint(f);
    u32 r = (u + 0x7fffu + ((u >> 16) & 1u)) >> 16;  // RNE bf16
    return (u16)r;
}
__device__ __forceinline__ u16 bfbits(float f) {
    __hip_bfloat16 h = __float2bfloat16(f);
    return *reinterpret_cast<u16*>(&h);
}
__device__ __forceinline__ float b2f(u16 b) {
    return __uint_as_float(((u32)b) << 16);
}

#define MFMA16(a, b, c) __builtin_amdgcn_mfma_f32_16x16x32_bf16(a, b, c, 0, 0, 0)
#define GLDS(gp, lp)                                                              \
    __builtin_amdgcn_global_load_lds((const __attribute__((address_space(1))) void*)(gp), \
                                     (__attribute__((address_space(3))) void*)(lp), 16, 0, 0)

// ---------------- elementwise: f32 -> bf16 ----------------
__global__ void k_f2b(const float* __restrict__ in, u16* __restrict__ out, int n4) {
    int i = blockIdx.x * 256 + threadIdx.x;
    if (i >= n4) return;
    float4 v = ((const float4*)in)[i];
    ushort4 o;
    o.x = f2b(v.x); o.y = f2b(v.y); o.z = f2b(v.z); o.w = f2b(v.w);
    ((ushort4*)out)[i] = o;
}

// ---------------- weight transpose+convert: W[K,N] f32 -> Wt[N,K] bf16 ----------------
__global__ void k_wtrans(const float* __restrict__ W, u16* __restrict__ Wt, int K, int N) {
    __shared__ float t[32][33];
    int bx = blockIdx.x * 32, by = blockIdx.y * 32;
    int tx = threadIdx.x, ty = threadIdx.y;
    for (int i = 0; i < 32; i += 8)
        t[ty + i][tx] = W[(size_t)(by + ty + i) * N + bx + tx];
    __syncthreads();
    for (int i = 0; i < 32; i += 8)
        Wt[(size_t)(bx + ty + i) * K + by + tx] = f2b(t[tx][ty + i]);
}

// ---------------- GEMM 128x128: C = A @ Bt^T.  EPI 0: f32 store. EPI 1: bf16(relu(acc+bias)) ----------------
template <int EPI>
__global__ __launch_bounds__(256) void gemm_bt(const u16* __restrict__ A, const u16* __restrict__ Bt,
                                               void* __restrict__ Cv, int M, int N, int K,
                                               const float* __restrict__ bias) {
    __shared__ __align__(16) short lA[128 * 64];
    __shared__ __align__(16) short lB[128 * 64];
    const int tid = threadIdx.x, lane = tid & 63, w = tid >> 6;
    const int l15 = lane & 15, lg = lane >> 4;
    const int bm = blockIdx.y, bn = blockIdx.x;
    const int wr = w >> 1, wc = w & 1;
    const int m0 = bm * 128, n0 = bn * 128;
    f32x4 acc[4][4] = {};

    for (int k0 = 0; k0 < K; k0 += 64) {
        #pragma unroll
        for (int i = 0; i < 4; i++) {
            int chunk = w * 4 + i;
            int arow = m0 + chunk * 8 + (lane >> 3);
            GLDS(A + (size_t)arow * K + k0 + (lane & 7) * 8, (short*)lA + chunk * 512);
            int brow = n0 + chunk * 8 + (lane >> 3);
            GLDS(Bt + (size_t)brow * K + k0 + (lane & 7) * 8, (short*)lB + chunk * 512);
        }
        __syncthreads();
        #pragma unroll
        for (int ks = 0; ks < 2; ks++) {
            s16x8 af[4], bfr[4];
            #pragma unroll
            for (int m = 0; m < 4; m++)
                af[m] = *(const s16x8*)&lA[(wr * 64 + m * 16 + l15) * 64 + ks * 32 + lg * 8];
            #pragma unroll
            for (int n = 0; n < 4; n++)
                bfr[n] = *(const s16x8*)&lB[(wc * 64 + n * 16 + l15) * 64 + ks * 32 + lg * 8];
            #pragma unroll
            for (int m = 0; m < 4; m++)
                #pragma unroll
                for (int n = 0; n < 4; n++)
                    acc[m][n] = MFMA16(af[m], bfr[n], acc[m][n]);
        }
        __syncthreads();
    }
    const int rbase = m0 + wr * 64, cbase = n0 + wc * 64;
    #pragma unroll
    for (int m = 0; m < 4; m++)
        #pragma unroll
        for (int n = 0; n < 4; n++) {
            int col = cbase + n * 16 + l15;
            int row0 = rbase + m * 16 + lg * 4;
            if (EPI == 0) {
                float* C = (float*)Cv;
                #pragma unroll
                for (int r = 0; r < 4; r++)
                    C[(size_t)(row0 + r) * N + col] = acc[m][n][r];
            } else {
                u16* C = (u16*)Cv;
                float bv = bias[col];
                #pragma unroll
                for (int r = 0; r < 4; r++)
                    C[(size_t)(row0 + r) * N + col] = bfbits(fmaxf(acc[m][n][r] + bv, 0.f));
            }
        }
}

// ---------------- GEMM 128x64 (for N=1024 shapes: more blocks, 2/CU) ----------------
__global__ __launch_bounds__(256) void gemm_bt64(const u16* __restrict__ A, const u16* __restrict__ Bt,
                                                 float* __restrict__ C, int M, int N, int K) {
    __shared__ __align__(16) short lA[128 * 64];
    __shared__ __align__(16) short lB[64 * 64];
    const int tid = threadIdx.x, lane = tid & 63, w = tid >> 6;
    const int l15 = lane & 15, lg = lane >> 4;
    const int m0 = blockIdx.y * 128, n0 = blockIdx.x * 64;
    f32x4 acc[2][4] = {};

    for (int k0 = 0; k0 < K; k0 += 64) {
        #pragma unroll
        for (int i = 0; i < 4; i++) {
            int chunk = w * 4 + i;
            int arow = m0 + chunk * 8 + (lane >> 3);
            GLDS(A + (size_t)arow * K + k0 + (lane & 7) * 8, (short*)lA + chunk * 512);
        }
        #pragma unroll
        for (int i = 0; i < 2; i++) {
            int chunk = w * 2 + i;
            int brow = n0 + chunk * 8 + (lane >> 3);
            GLDS(Bt + (size_t)brow * K + k0 + (lane & 7) * 8, (short*)lB + chunk * 512);
        }
        __syncthreads();
        #pragma unroll
        for (int ks = 0; ks < 2; ks++) {
            s16x8 af[2], bfr[4];
            #pragma unroll
            for (int m = 0; m < 2; m++)
                af[m] = *(const s16x8*)&lA[(w * 32 + m * 16 + l15) * 64 + ks * 32 + lg * 8];
            #pragma unroll
            for (int n = 0; n < 4; n++)
                bfr[n] = *(const s16x8*)&lB[(n * 16 + l15) * 64 + ks * 32 + lg * 8];
            #pragma unroll
            for (int m = 0; m < 2; m++)
                #pragma unroll
                for (int n = 0; n < 4; n++)
                    acc[m][n] = MFMA16(af[m], bfr[n], acc[m][n]);
        }
        __syncthreads();
    }
    #pragma unroll
    for (int m = 0; m < 2; m++)
        #pragma unroll
        for (int n = 0; n < 4; n++) {
            int col = n0 + n * 16 + l15;
            int row0 = m0 + w * 32 + m * 16 + lg * 4;
            #pragma unroll
            for (int r = 0; r < 4; r++)
                C[(size_t)(row0 + r) * N + col] = acc[m][n][r];
        }
}

// ---------------- QKV epilogue (strided QKV buffer): +bias, +rel -> two bf16 variants ----------------
__global__ void k_epi_qk2(const float* __restrict__ QKVf, int coff, const float* __restrict__ bias,
                          const float* __restrict__ rel, u16* __restrict__ Pa, u16* __restrict__ Pc, int n4) {
    int i = blockIdx.x * 256 + threadIdx.x;
    if (i >= n4) return;
    int f = i * 4;
    int row = f >> 10, col = f & 1023;
    float4 v = *(const float4*)(QKVf + (size_t)row * 3072 + coff + col);
    int d = f & 63;
    float4 b = *(const float4*)(bias + col);
    float4 r0 = *(const float4*)(rel + d);
    float4 r1 = *(const float4*)(rel + 64 + d);
    ushort4 oa, oc;
    oa.x = f2b(v.x + b.x + r0.x); oa.y = f2b(v.y + b.y + r0.y);
    oa.z = f2b(v.z + b.z + r0.z); oa.w = f2b(v.w + b.w + r0.w);
    oc.x = f2b(v.x + b.x + r1.x); oc.y = f2b(v.y + b.y + r1.y);
    oc.z = f2b(v.z + b.z + r1.z); oc.w = f2b(v.w + b.w + r1.w);
    ((ushort4*)Pa)[i] = oa;
    ((ushort4*)Pc)[i] = oc;
}

// ---------------- V transpose per group from strided QKV: -> Vt[g][d][l] bf16 ----------------
__global__ void k_vtrans2(const float* __restrict__ QKVf, const float* __restrict__ bv, u16* __restrict__ Vt) {
    __shared__ float t[64][65];
    const int g = blockIdx.y, lt = blockIdx.x;
    const int tx = threadIdx.x & 63, ty = threadIdx.x >> 6;  // 64 x 4
    const size_t gQ = (size_t)g * 65536;
    for (int i = 0; i < 64; i += 4) {
        int l = lt * 64 + ty + i;
        size_t f = gQ + (size_t)l * 64 + tx;  // flat index in [B*L, D] view
        t[ty + i][tx] = QKVf[(f >> 10) * 3072 + 2048 + (f & 1023)] + bv[f & 1023];
    }
    __syncthreads();
    for (int i = 0; i < 64; i += 4) {
        int d = ty + i;
        Vt[gQ + (size_t)d * 1024 + lt * 64 + tx] = f2b(t[tx][d]);
    }
}

// ---------------- stage A: S=QK^T, E=exp(S/8) -> linear bf16 blob + row denominators ----------------
// flat grid 1024 (XCD-swizzled -> (qt,g)), 4 waves; wave w owns q rows qt*64+w*16..+15, full k sweep.
// E blob layout = stage-B load order: [g][qt][w][it][ks][lane] x 16B.
__global__ __launch_bounds__(256) void k_qke(const u16* __restrict__ Q, const u16* __restrict__ K,
                                             u16* __restrict__ E, float* __restrict__ denom) {
    const int bid = blockIdx.x;
    const int xcd = bid & 7, j = bid >> 3;
    const int g = xcd * 8 + (j & 7), qt = j >> 3;
    const int tid = threadIdx.x, lane = tid & 63, w = tid >> 6;
    const int l15 = lane & 15, lg = lane >> 4;
    __shared__ __align__(16) float lE[4][16][68];

    const int q0 = qt * 64 + w * 16;
    const size_t gQ = (size_t)g * 65536;
    const size_t ebase = ((((size_t)g * 16 + qt) * 4 + w) * 16384) + (size_t)lane * 8;
    const float scale = 0.125f;

    s16x8 qf[2];
    #pragma unroll
    for (int ks = 0; ks < 2; ks++)
        qf[ks] = *(const s16x8*)(Q + gQ + (size_t)(q0 + l15) * 64 + ks * 32 + lg * 8);

    float la[4] = {0.f, 0.f, 0.f, 0.f};

    #pragma unroll 1
    for (int it = 0; it < 16; it++) {
        const int kb = it * 64;
        f32x4 sa[4] = {};
        #pragma unroll
        for (int ks = 0; ks < 2; ks++)
            #pragma unroll
            for (int n = 0; n < 4; n++) {
                s16x8 kf = *(const s16x8*)(K + gQ + (size_t)(kb + n * 16 + l15) * 64 + ks * 32 + lg * 8);
                sa[n] = MFMA16(qf[ks], kf, sa[n]);
            }
        #pragma unroll
        for (int n = 0; n < 4; n++)
            #pragma unroll
            for (int r = 0; r < 4; r++) {
                float e = __expf(sa[n][r] * scale);
                la[r] += e;
                lE[w][lg * 4 + r][n * 16 + l15] = e;
            }
        #pragma unroll
        for (int ks = 0; ks < 2; ks++) {
            const float* ep = &lE[w][l15][ks * 32 + lg * 8];
            float4 e0 = *(const float4*)ep, e1 = *(const float4*)(ep + 4);
            uint4 st;
            st.x = (u32)f2b(e0.x) | ((u32)f2b(e0.y) << 16);
            st.y = (u32)f2b(e0.z) | ((u32)f2b(e0.w) << 16);
            st.z = (u32)f2b(e1.x) | ((u32)f2b(e1.y) << 16);
            st.w = (u32)f2b(e1.z) | ((u32)f2b(e1.w) << 16);
            *(uint4*)(E + ebase + (size_t)it * 1024 + ks * 512) = st;
        }
    }
    #pragma unroll
    for (int r = 0; r < 4; r++)
        #pragma unroll
        for (int m = 8; m >= 1; m >>= 1)
            la[r] += __shfl_xor(la[r], m);
    if (l15 == 0) {
        #pragma unroll
        for (int r = 0; r < 4; r++)
            denom[g * 1024 + q0 + lg * 4 + r] = la[r];
    }
}

// ---------------- stage B: ctx = (E o M) @ V / denom  (pure stream, short dep chains) ----------------
// PHASE 0: write normalized partial ctx f32. PHASE 1: add to partial, write bf16 ctx.
template <int PHASE>
__global__ __launch_bounds__(256) void k_pv(const u16* __restrict__ E, const u16* __restrict__ Vt,
                                            const float* __restrict__ mask, const float* __restrict__ denom,
                                            float* __restrict__ ctxP, u16* __restrict__ ctx) {
    const int bid = blockIdx.x;
    const int xcd = bid & 7, j = bid >> 3;
    const int g = xcd * 8 + (j & 7), qt = j >> 3;
    const int tid = threadIdx.x, lane = tid & 63, w = tid >> 6;
    const int l15 = lane & 15, lg = lane >> 4;

    const int q0 = qt * 64 + w * 16;
    const size_t gQ = (size_t)g * 65536;
    const float* __restrict__ mrow = mask + (size_t)g * 1048576 + (size_t)(q0 + l15) * 1024 + lg * 8;
    const size_t ebase = ((((size_t)g * 16 + qt) * 4 + w) * 16384) + (size_t)lane * 8;

    f32x4 ca[4] = {};

    #pragma unroll 2
    for (int it = 0; it < 16; it++) {
        const int kb = it * 64;
        // all loads independent -> issue together, counted waits
        s16x8 ev[2];
        float4 m0[2], m1[2];
        #pragma unroll
        for (int ks = 0; ks < 2; ks++) {
            ev[ks] = *(const s16x8*)(E + ebase + (size_t)it * 1024 + ks * 512);
            m0[ks] = *(const float4*)(mrow + kb + ks * 32);
            m1[ks] = *(const float4*)(mrow + kb + ks * 32 + 4);
        }
        #pragma unroll
        for (int ks = 0; ks < 2; ks++) {
            union { s16x8 v; u16 u[8]; } pf;
            pf.u[0] = f2b(b2f((u16)ev[ks][0]) * m0[ks].x);
            pf.u[1] = f2b(b2f((u16)ev[ks][1]) * m0[ks].y);
            pf.u[2] = f2b(b2f((u16)ev[ks][2]) * m0[ks].z);
            pf.u[3] = f2b(b2f((u16)ev[ks][3]) * m0[ks].w);
            pf.u[4] = f2b(b2f((u16)ev[ks][4]) * m1[ks].x);
            pf.u[5] = f2b(b2f((u16)ev[ks][5]) * m1[ks].y);
            pf.u[6] = f2b(b2f((u16)ev[ks][6]) * m1[ks].z);
            pf.u[7] = f2b(b2f((u16)ev[ks][7]) * m1[ks].w);
            #pragma unroll
            for (int d = 0; d < 4; d++) {
                s16x8 vf = *(const s16x8*)(Vt + gQ + (size_t)(d * 16 + l15) * 1024 + kb + ks * 32 + lg * 8);
                ca[d] = MFMA16(pf.v, vf, ca[d]);
            }
        }
    }
    float il[4];
    #pragma unroll
    for (int r = 0; r < 4; r++)
        il[r] = 1.f / denom[g * 1024 + q0 + lg * 4 + r];
    #pragma unroll
    for (int r = 0; r < 4; r++) {
        int row = q0 + lg * 4 + r;
        #pragma unroll
        for (int d = 0; d < 4; d++) {
            size_t idx = gQ + (size_t)row * 64 + d * 16 + l15;
            if (PHASE == 0) {
                ctxP[idx] = ca[d][r] * il[r];
            } else {
                ctx[idx] = f2b(ctxP[idx] + ca[d][r] * il[r]);
            }
        }
    }
}

// ---------------- row LayerNorm: t = a[row]+bias+resid[row]; out = LN(t)*g+b (D=1024) ----------------
__global__ __launch_bounds__(256) void k_ln(const float* __restrict__ a, const float* __restrict__ bias,
                                            const float* __restrict__ resid, const float* __restrict__ gamma,
                                            const float* __restrict__ beta, float* __restrict__ out,
                                            u16* __restrict__ outb) {
    const int row = blockIdx.x, tid = threadIdx.x;
    const size_t base = (size_t)row * 1024 + tid * 4;
    float4 av = *(const float4*)(a + base);
    float4 rv = *(const float4*)(resid + base);
    float4 bv = *(const float4*)(bias + tid * 4);
    float t0 = av.x + rv.x + bv.x, t1 = av.y + rv.y + bv.y;
    float t2 = av.z + rv.z + bv.z, t3 = av.w + rv.w + bv.w;
    __shared__ float red[4];
    float s = t0 + t1 + t2 + t3;
    #pragma unroll
    for (int m = 32; m >= 1; m >>= 1) s += __shfl_xor(s, m);
    int w = tid >> 6;
    if ((tid & 63) == 0) red[w] = s;
    __syncthreads();
    float mean = (red[0] + red[1] + red[2] + red[3]) * (1.f / 1024.f);
    float d0 = t0 - mean, d1 = t1 - mean, d2 = t2 - mean, d3 = t3 - mean;
    float q = d0 * d0 + d1 * d1 + d2 * d2 + d3 * d3;
    __syncthreads();
    #pragma unroll
    for (int m = 32; m >= 1; m >>= 1) q += __shfl_xor(q, m);
    if ((tid & 63) == 0) red[w] = q;
    __syncthreads();
    float var = (red[0] + red[1] + red[2] + red[3]) * (1.f / 1024.f);
    float rs = rsqrtf(var + 1e-5f);
    float4 gv = *(const float4*)(gamma + tid * 4);
    float4 bev = *(const float4*)(beta + tid * 4);
    float o0 = d0 * rs * gv.x + bev.x, o1 = d1 * rs * gv.y + bev.y;
    float o2 = d2 * rs * gv.z + bev.z, o3 = d3 * rs * gv.w + bev.w;
    *(float4*)(out + base) = make_float4(o0, o1, o2, o3);
    if (outb) {
        ushort4 ob;
        ob.x = f2b(o0); ob.y = f2b(o1); ob.z = f2b(o2); ob.w = f2b(o3);
        *(ushort4*)(outb + base) = ob;
    }
}

extern "C" void kernel_launch(void* const* d_in, const int* in_sizes, int n_in,
                              void* d_out, int out_size, void* d_ws, size_t ws_size,
                              hipStream_t stream) {
    const float* x    = (const float*)d_in[0];
    const float* adjm = (const float*)d_in[1];
    const float* comm = (const float*)d_in[2];
    const float* rel  = (const float*)d_in[3];
    const float* Wq   = (const float*)d_in[4];
    const float* bq   = (const float*)d_in[5];
    const float* Wk   = (const float*)d_in[6];
    const float* bk   = (const float*)d_in[7];
    const float* Wv   = (const float*)d_in[8];
    const float* bv   = (const float*)d_in[9];
    const float* Wo   = (const float*)d_in[10];
    const float* bo   = (const float*)d_in[11];
    const float* g1   = (const float*)d_in[12];
    const float* be1  = (const float*)d_in[13];
    const float* W1   = (const float*)d_in[14];
    const float* b1   = (const float*)d_in[15];
    const float* W2   = (const float*)d_in[16];
    const float* b2   = (const float*)d_in[17];
    const float* g2   = (const float*)d_in[18];
    const float* be2  = (const float*)d_in[19];
    float* out = (float*)d_out;

    char* ws = (char*)d_ws;
    const size_t MB = 1048576;
    u16*   xb    = (u16*)(ws + 0 * MB);      // 8 MiB (dead after QKV gemm)
    u16*   Wqkvt = (u16*)(ws + 8 * MB);      // 6 MiB
    u16*   Wot   = (u16*)(ws + 14 * MB);     // 2 MiB
    u16*   W1t   = (u16*)(ws + 16 * MB);     // 8 MiB
    u16*   W2t   = (u16*)(ws + 24 * MB);     // 8 MiB (live through FFN2)
    float* QKVf  = (float*)(ws + 32 * MB);   // 48 MiB [32,80)
    u16*   Qab   = (u16*)(ws + 80 * MB);     // 8 MiB each [80,120)
    u16*   Qcb   = (u16*)(ws + 88 * MB);
    u16*   Kab   = (u16*)(ws + 96 * MB);
    u16*   Kcb   = (u16*)(ws + 104 * MB);
    u16*   Vtb   = (u16*)(ws + 112 * MB);
    u16*   Eb    = (u16*)(ws + 120 * MB);    // 128 MiB [120,248) (per-map, reused)
    float* denA  = (float*)(ws + 248 * MB);  // 256 KiB
    float* denC  = denA + 65536;             // 256 KiB
    float* ctxP  = (float*)(ws + 249 * MB);  // 16 MiB [249,265)
    u16*   ctx   = (u16*)(ws + 265 * MB);    // 8 MiB [265,273)
    float* ctxWo = (float*)(ws + 32 * MB);   // reuse QKVf
    float* out1  = (float*)(ws + 48 * MB);   // live to LN2
    u16*   out1b = (u16*)(ws + 64 * MB);
    u16*   rb    = (u16*)(ws + 80 * MB);     // 32 MiB reuse attn inputs (dead)
    float* ff2   = (float*)(ws + 0 * MB);    // 16 MiB reuse (xb+Wqkvt+Wot+W1t dead)

    dim3 tb(32, 8);
    // 1. casts / weight prep
    k_f2b<<<4096, 256, 0, stream>>>(x, xb, 1048576);
    k_wtrans<<<dim3(32, 32), tb, 0, stream>>>(Wq, Wqkvt, 1024, 1024);
    k_wtrans<<<dim3(32, 32), tb, 0, stream>>>(Wk, Wqkvt + 1024 * 1024, 1024, 1024);
    k_wtrans<<<dim3(32, 32), tb, 0, stream>>>(Wv, Wqkvt + 2 * 1024 * 1024, 1024, 1024);
    k_wtrans<<<dim3(32, 32), tb, 0, stream>>>(Wo, Wot, 1024, 1024);
    k_wtrans<<<dim3(128, 32), tb, 0, stream>>>(W1, W1t, 1024, 4096);
    k_wtrans<<<dim3(32, 128), tb, 0, stream>>>(W2, W2t, 4096, 1024);
    // 2. fused QKV projection
    gemm_bt<0><<<dim3(24, 32), 256, 0, stream>>>(xb, Wqkvt, QKVf, 4096, 3072, 1024, nullptr);
    // 3. epilogues
    k_epi_qk2<<<4096, 256, 0, stream>>>(QKVf, 0, bq, rel, Qab, Qcb, 1048576);
    k_epi_qk2<<<4096, 256, 0, stream>>>(QKVf, 1024, bk, rel, Kab, Kcb, 1048576);
    k_vtrans2<<<dim3(16, 64), 256, 0, stream>>>(QKVf, bv, Vtb);
    // 4. attention: two-stage per map (E buffer reused; stream-ordered)
    k_qke<<<1024, 256, 0, stream>>>(Qab, Kab, Eb, denA);
    k_pv<0><<<1024, 256, 0, stream>>>(Eb, Vtb, adjm, denA, ctxP, nullptr);
    k_qke<<<1024, 256, 0, stream>>>(Qcb, Kcb, Eb, denC);
    k_pv<1><<<1024, 256, 0, stream>>>(Eb, Vtb, comm, denC, ctxP, ctx);
    // 5. output projection + LN1
    gemm_bt64<<<dim3(16, 32), 256, 0, stream>>>(ctx, Wot, ctxWo, 4096, 1024, 1024);
    k_ln<<<4096, 256, 0, stream>>>(ctxWo, bo, x, g1, be1, out1, out1b);
    // 6. FFN
    gemm_bt<1><<<dim3(32, 32), 256, 0, stream>>>(out1b, W1t, rb, 4096, 4096, 1024, b1);
    gemm_bt64<<<dim3(16, 32), 256, 0, stream>>>(rb, W2t, ff2, 4096, 1024, 4096);
    // 7. LN2 -> final output
    k_ln<<<4096, 256, 0, stream>>>(ff2, b2, out1, g2, be2, out, nullptr);
}

// Round 5
// 600.014 us; speedup vs baseline: 1.1176x; 1.1176x over previous
//
#include <hip/hip_runtime.h>
#include <hip/hip_bf16.h>

typedef __attribute__((ext_vector_type(8))) short s16x8;
typedef __attribute__((ext_vector_type(4))) float f32x4;
typedef unsigned short u16;
typedef unsigned int u32;

__device__ __forceinline__ u16 f2b(float f) {
    u32 u = __float_as_uint(f);
    u32 r = (u + 0x7fffu + ((u >> 16) & 1u)) >> 16;  // RNE bf16
    return (u16)r;
}

#define MFMA16(a, b, c) __builtin_amdgcn_mfma_f32_16x16x32_bf16(a, b, c, 0, 0, 0)
#define GLDS(gp, lp)                                                              \
    __builtin_amdgcn_global_load_lds((const __attribute__((address_space(1))) void*)(gp), \
                                     (__attribute__((address_space(3))) void*)(lp), 16, 0, 0)
#define SB() __builtin_amdgcn_sched_barrier(0)

// ---------------- elementwise: f32 -> bf16 ----------------
__global__ void k_f2b(const float* __restrict__ in, u16* __restrict__ out, int n4) {
    int i = blockIdx.x * 256 + threadIdx.x;
    if (i >= n4) return;
    float4 v = ((const float4*)in)[i];
    ushort4 o;
    o.x = f2b(v.x); o.y = f2b(v.y); o.z = f2b(v.z); o.w = f2b(v.w);
    ((ushort4*)out)[i] = o;
}

// ---------------- weight transpose+convert: W[K,N] f32 -> Wt[N,K] bf16 ----------------
__global__ void k_wtrans(const float* __restrict__ W, u16* __restrict__ Wt, int K, int N) {
    __shared__ float t[32][33];
    int bx = blockIdx.x * 32, by = blockIdx.y * 32;
    int tx = threadIdx.x, ty = threadIdx.y;
    for (int i = 0; i < 32; i += 8)
        t[ty + i][tx] = W[(size_t)(by + ty + i) * N + bx + tx];
    __syncthreads();
    for (int i = 0; i < 32; i += 8)
        Wt[(size_t)(bx + ty + i) * K + by + tx] = f2b(t[tx][ty + i]);
}

// ---------------- fused QKV GEMM: [4096,1024]@[3072,1024]^T, epilogue writes Qa/Qc/Ka/Kc/Vt bf16 ----------------
__global__ __launch_bounds__(256) void gemm_qkv(const u16* __restrict__ A, const u16* __restrict__ Bt,
                                                const float* __restrict__ bq, const float* __restrict__ bk,
                                                const float* __restrict__ bv, const float* __restrict__ rel,
                                                u16* __restrict__ Qa, u16* __restrict__ Qc,
                                                u16* __restrict__ Ka, u16* __restrict__ Kc,
                                                u16* __restrict__ Vt) {
    __shared__ __align__(16) short lA[128 * 64];
    __shared__ __align__(16) short lB[128 * 64];
    const int tid = threadIdx.x, lane = tid & 63, w = tid >> 6;
    const int l15 = lane & 15, lg = lane >> 4;
    const int wr = w >> 1, wc = w & 1;
    const int m0 = blockIdx.y * 128, n0 = blockIdx.x * 128;
    const int KK = 1024;
    f32x4 acc[4][4] = {};

    for (int k0 = 0; k0 < KK; k0 += 64) {
        #pragma unroll
        for (int i = 0; i < 4; i++) {
            int chunk = w * 4 + i;
            int arow = m0 + chunk * 8 + (lane >> 3);
            GLDS(A + (size_t)arow * KK + k0 + (lane & 7) * 8, (short*)lA + chunk * 512);
            int brow = n0 + chunk * 8 + (lane >> 3);
            GLDS(Bt + (size_t)brow * KK + k0 + (lane & 7) * 8, (short*)lB + chunk * 512);
        }
        __syncthreads();
        #pragma unroll
        for (int ks = 0; ks < 2; ks++) {
            s16x8 af[4], bfr[4];
            #pragma unroll
            for (int m = 0; m < 4; m++)
                af[m] = *(const s16x8*)&lA[(wr * 64 + m * 16 + l15) * 64 + ks * 32 + lg * 8];
            #pragma unroll
            for (int n = 0; n < 4; n++)
                bfr[n] = *(const s16x8*)&lB[(wc * 64 + n * 16 + l15) * 64 + ks * 32 + lg * 8];
            #pragma unroll
            for (int m = 0; m < 4; m++)
                #pragma unroll
                for (int n = 0; n < 4; n++)
                    acc[m][n] = MFMA16(af[m], bfr[n], acc[m][n]);
        }
        __syncthreads();
    }
    const int rbase = m0 + wr * 64, cbase = n0 + wc * 64;
    const int seg = cbase >> 10;  // uniform per block (128-wide tiles)
    #pragma unroll
    for (int m = 0; m < 4; m++)
        #pragma unroll
        for (int n = 0; n < 4; n++) {
            int col = cbase + n * 16 + l15;
            int c1 = col & 1023, d = col & 63;
            int row0 = rbase + m * 16 + lg * 4;
            if (seg == 0) {
                float bb = bq[c1], r0 = rel[d], r1 = rel[64 + d];
                #pragma unroll
                for (int r = 0; r < 4; r++) {
                    float v = acc[m][n][r] + bb;
                    size_t o = (size_t)(row0 + r) * 1024 + c1;
                    Qa[o] = f2b(v + r0);
                    Qc[o] = f2b(v + r1);
                }
            } else if (seg == 1) {
                float bb = bk[c1], r0 = rel[d], r1 = rel[64 + d];
                #pragma unroll
                for (int r = 0; r < 4; r++) {
                    float v = acc[m][n][r] + bb;
                    size_t o = (size_t)(row0 + r) * 1024 + c1;
                    Ka[o] = f2b(v + r0);
                    Kc[o] = f2b(v + r1);
                }
            } else {
                float bb = bv[c1];
                #pragma unroll
                for (int r = 0; r < 4; r++) {
                    int row = row0 + r;
                    // Vt[g][d][l'] with g=row>>6, l'=(row&63)*16+(c1>>6)
                    size_t o = (size_t)(row >> 6) * 65536 + (size_t)d * 1024 + (row & 63) * 16 + (c1 >> 6);
                    Vt[o] = f2b(acc[m][n][r] + bb);
                }
            }
        }
}

// ---------------- GEMM 128x128, EPI 1: bf16(relu(acc+bias)) ----------------
template <int EPI>
__global__ __launch_bounds__(256) void gemm_bt(const u16* __restrict__ A, const u16* __restrict__ Bt,
                                               void* __restrict__ Cv, int M, int N, int K,
                                               const float* __restrict__ bias) {
    __shared__ __align__(16) short lA[128 * 64];
    __shared__ __align__(16) short lB[128 * 64];
    const int tid = threadIdx.x, lane = tid & 63, w = tid >> 6;
    const int l15 = lane & 15, lg = lane >> 4;
    const int wr = w >> 1, wc = w & 1;
    const int m0 = blockIdx.y * 128, n0 = blockIdx.x * 128;
    f32x4 acc[4][4] = {};

    for (int k0 = 0; k0 < K; k0 += 64) {
        #pragma unroll
        for (int i = 0; i < 4; i++) {
            int chunk = w * 4 + i;
            int arow = m0 + chunk * 8 + (lane >> 3);
            GLDS(A + (size_t)arow * K + k0 + (lane & 7) * 8, (short*)lA + chunk * 512);
            int brow = n0 + chunk * 8 + (lane >> 3);
            GLDS(Bt + (size_t)brow * K + k0 + (lane & 7) * 8, (short*)lB + chunk * 512);
        }
        __syncthreads();
        #pragma unroll
        for (int ks = 0; ks < 2; ks++) {
            s16x8 af[4], bfr[4];
            #pragma unroll
            for (int m = 0; m < 4; m++)
                af[m] = *(const s16x8*)&lA[(wr * 64 + m * 16 + l15) * 64 + ks * 32 + lg * 8];
            #pragma unroll
            for (int n = 0; n < 4; n++)
                bfr[n] = *(const s16x8*)&lB[(wc * 64 + n * 16 + l15) * 64 + ks * 32 + lg * 8];
            #pragma unroll
            for (int m = 0; m < 4; m++)
                #pragma unroll
                for (int n = 0; n < 4; n++)
                    acc[m][n] = MFMA16(af[m], bfr[n], acc[m][n]);
        }
        __syncthreads();
    }
    const int rbase = m0 + wr * 64, cbase = n0 + wc * 64;
    #pragma unroll
    for (int m = 0; m < 4; m++)
        #pragma unroll
        for (int n = 0; n < 4; n++) {
            int col = cbase + n * 16 + l15;
            int row0 = rbase + m * 16 + lg * 4;
            u16* C = (u16*)Cv;
            float bv = bias[col];
            #pragma unroll
            for (int r = 0; r < 4; r++)
                C[(size_t)(row0 + r) * N + col] = f2b(fmaxf(acc[m][n][r] + bv, 0.f));
        }
}

// ---------------- GEMM 128x64 f32-out ----------------
__global__ __launch_bounds__(256) void gemm_bt64(const u16* __restrict__ A, const u16* __restrict__ Bt,
                                                 float* __restrict__ C, int M, int N, int K) {
    __shared__ __align__(16) short lA[128 * 64];
    __shared__ __align__(16) short lB[64 * 64];
    const int tid = threadIdx.x, lane = tid & 63, w = tid >> 6;
    const int l15 = lane & 15, lg = lane >> 4;
    const int m0 = blockIdx.y * 128, n0 = blockIdx.x * 64;
    f32x4 acc[2][4] = {};

    for (int k0 = 0; k0 < K; k0 += 64) {
        #pragma unroll
        for (int i = 0; i < 4; i++) {
            int chunk = w * 4 + i;
            int arow = m0 + chunk * 8 + (lane >> 3);
            GLDS(A + (size_t)arow * K + k0 + (lane & 7) * 8, (short*)lA + chunk * 512);
        }
        #pragma unroll
        for (int i = 0; i < 2; i++) {
            int chunk = w * 2 + i;
            int brow = n0 + chunk * 8 + (lane >> 3);
            GLDS(Bt + (size_t)brow * K + k0 + (lane & 7) * 8, (short*)lB + chunk * 512);
        }
        __syncthreads();
        #pragma unroll
        for (int ks = 0; ks < 2; ks++) {
            s16x8 af[2], bfr[4];
            #pragma unroll
            for (int m = 0; m < 2; m++)
                af[m] = *(const s16x8*)&lA[(w * 32 + m * 16 + l15) * 64 + ks * 32 + lg * 8];
            #pragma unroll
            for (int n = 0; n < 4; n++)
                bfr[n] = *(const s16x8*)&lB[(n * 16 + l15) * 64 + ks * 32 + lg * 8];
            #pragma unroll
            for (int m = 0; m < 2; m++)
                #pragma unroll
                for (int n = 0; n < 4; n++)
                    acc[m][n] = MFMA16(af[m], bfr[n], acc[m][n]);
        }
        __syncthreads();
    }
    #pragma unroll
    for (int m = 0; m < 2; m++)
        #pragma unroll
        for (int n = 0; n < 4; n++) {
            int col = n0 + n * 16 + l15;
            int row0 = m0 + w * 32 + m * 16 + lg * 4;
            #pragma unroll
            for (int r = 0; r < 4; r++)
                C[(size_t)(row0 + r) * N + col] = acc[m][n][r];
        }
}

// ---------------- fused single-pass attention, map on blockIdx.z ----------------
// Per iter issue order (enforced by sched_barrier): K loads -> V+M loads -> compute.
// QK's wait leaves V+M outstanding; they stream under exp/LDS; PV drains them ~650cy later.
__global__ __launch_bounds__(256) void k_attnf(const u16* __restrict__ Qa, const u16* __restrict__ Qc,
                                               const u16* __restrict__ Ka, const u16* __restrict__ Kc,
                                               const u16* __restrict__ Vt,
                                               const float* __restrict__ adjm, const float* __restrict__ comm,
                                               float* __restrict__ ctxA, float* __restrict__ ctxC) {
    const int bid = blockIdx.x;
    const int xcd = bid & 7, j = bid >> 3;
    const int g = xcd * 8 + (j & 7), qt = j >> 3;
    const int s = blockIdx.z;
    const u16* __restrict__ Q = s ? Qc : Qa;
    const u16* __restrict__ K = s ? Kc : Ka;
    const float* __restrict__ mask = s ? comm : adjm;
    float* __restrict__ ctxp = s ? ctxC : ctxA;

    const int tid = threadIdx.x, lane = tid & 63, w = tid >> 6;
    const int l15 = lane & 15, lg = lane >> 4;
    __shared__ __align__(16) float lE[4][16][68];

    const int q0 = qt * 64 + w * 16;
    const size_t gQ = (size_t)g * 65536;
    const float* __restrict__ mrow = mask + (size_t)g * 1048576 + (size_t)(q0 + l15) * 1024 + lg * 8;
    const float scale = 0.125f;

    s16x8 qf[2];
    #pragma unroll
    for (int ks = 0; ks < 2; ks++)
        qf[ks] = *(const s16x8*)(Q + gQ + (size_t)(q0 + l15) * 64 + ks * 32 + lg * 8);

    f32x4 ca[4] = {};
    float la[4] = {0.f, 0.f, 0.f, 0.f};

    #pragma unroll 1
    for (int it = 0; it < 16; it++) {
        const int kb = it * 64;
        // --- issue K loads FIRST (oldest) ---
        s16x8 kf[8];
        #pragma unroll
        for (int ks = 0; ks < 2; ks++)
            #pragma unroll
            for (int n = 0; n < 4; n++)
                kf[ks * 4 + n] = *(const s16x8*)(K + gQ + (size_t)(kb + n * 16 + l15) * 64 + ks * 32 + lg * 8);
        SB();
        // --- then V + mask loads (stay outstanding across QK/exp/LDS) ---
        s16x8 vf[8];
        float4 mf[4];
        #pragma unroll
        for (int ks = 0; ks < 2; ks++)
            #pragma unroll
            for (int d = 0; d < 4; d++)
                vf[ks * 4 + d] = *(const s16x8*)(Vt + gQ + (size_t)(d * 16 + l15) * 1024 + kb + ks * 32 + lg * 8);
        #pragma unroll
        for (int ks = 0; ks < 2; ks++) {
            mf[ks * 2 + 0] = *(const float4*)(mrow + kb + ks * 32);
            mf[ks * 2 + 1] = *(const float4*)(mrow + kb + ks * 32 + 4);
        }
        SB();
        // --- QK^T (waits only on kf; vf/mf remain in flight) ---
        f32x4 sa[4] = {};
        #pragma unroll
        for (int ks = 0; ks < 2; ks++)
            #pragma unroll
            for (int n = 0; n < 4; n++)
                sa[n] = MFMA16(qf[ks], kf[ks * 4 + n], sa[n]);
        // --- exp (C-layout) -> LDS -> A-layout ---
        #pragma unroll
        for (int n = 0; n < 4; n++)
            #pragma unroll
            for (int r = 0; r < 4; r++) {
                float e = __expf(sa[n][r] * scale);
                la[r] += e;
                lE[w][lg * 4 + r][n * 16 + l15] = e;
            }
        // --- mask-mul + pack + PV ---
        #pragma unroll
        for (int ks = 0; ks < 2; ks++) {
            const float* ep = &lE[w][l15][ks * 32 + lg * 8];
            float4 e0 = *(const float4*)ep, e1 = *(const float4*)(ep + 4);
            union { s16x8 v; u16 u[8]; } pf;
            pf.u[0] = f2b(e0.x * mf[ks * 2].x); pf.u[1] = f2b(e0.y * mf[ks * 2].y);
            pf.u[2] = f2b(e0.z * mf[ks * 2].z); pf.u[3] = f2b(e0.w * mf[ks * 2].w);
            pf.u[4] = f2b(e1.x * mf[ks * 2 + 1].x); pf.u[5] = f2b(e1.y * mf[ks * 2 + 1].y);
            pf.u[6] = f2b(e1.z * mf[ks * 2 + 1].z); pf.u[7] = f2b(e1.w * mf[ks * 2 + 1].w);
            #pragma unroll
            for (int d = 0; d < 4; d++)
                ca[d] = MFMA16(pf.v, vf[ks * 4 + d], ca[d]);
        }
        SB();
    }
    // deferred denominator reduction over the 16-lane groups
    #pragma unroll
    for (int r = 0; r < 4; r++)
        #pragma unroll
        for (int m = 8; m >= 1; m >>= 1)
            la[r] += __shfl_xor(la[r], m);
    #pragma unroll
    for (int r = 0; r < 4; r++) {
        float il = 1.f / la[r];
        int row = q0 + lg * 4 + r;
        #pragma unroll
        for (int d = 0; d < 4; d++)
            ctxp[gQ + (size_t)row * 64 + d * 16 + l15] = ca[d][r] * il;
    }
}

// ---------------- combine the two maps' normalized partial contexts -> bf16 ----------------
__global__ void k_comb(const float* __restrict__ A, const float* __restrict__ C,
                       u16* __restrict__ out, int n4) {
    int i = blockIdx.x * 256 + threadIdx.x;
    if (i >= n4) return;
    float4 a = ((const float4*)A)[i];
    float4 c = ((const float4*)C)[i];
    ushort4 o;
    o.x = f2b(a.x + c.x); o.y = f2b(a.y + c.y);
    o.z = f2b(a.z + c.z); o.w = f2b(a.w + c.w);
    ((ushort4*)out)[i] = o;
}

// ---------------- row LayerNorm ----------------
__global__ __launch_bounds__(256) void k_ln(const float* __restrict__ a, const float* __restrict__ bias,
                                            const float* __restrict__ resid, const float* __restrict__ gamma,
                                            const float* __restrict__ beta, float* __restrict__ out,
                                            u16* __restrict__ outb) {
    const int row = blockIdx.x, tid = threadIdx.x;
    const size_t base = (size_t)row * 1024 + tid * 4;
    float4 av = *(const float4*)(a + base);
    float4 rv = *(const float4*)(resid + base);
    float4 bv = *(const float4*)(bias + tid * 4);
    float t0 = av.x + rv.x + bv.x, t1 = av.y + rv.y + bv.y;
    float t2 = av.z + rv.z + bv.z, t3 = av.w + rv.w + bv.w;
    __shared__ float red[4];
    float s = t0 + t1 + t2 + t3;
    #pragma unroll
    for (int m = 32; m >= 1; m >>= 1) s += __shfl_xor(s, m);
    int w = tid >> 6;
    if ((tid & 63) == 0) red[w] = s;
    __syncthreads();
    float mean = (red[0] + red[1] + red[2] + red[3]) * (1.f / 1024.f);
    float d0 = t0 - mean, d1 = t1 - mean, d2 = t2 - mean, d3 = t3 - mean;
    float q = d0 * d0 + d1 * d1 + d2 * d2 + d3 * d3;
    __syncthreads();
    #pragma unroll
    for (int m = 32; m >= 1; m >>= 1) q += __shfl_xor(q, m);
    if ((tid & 63) == 0) red[w] = q;
    __syncthreads();
    float var = (red[0] + red[1] + red[2] + red[3]) * (1.f / 1024.f);
    float rs = rsqrtf(var + 1e-5f);
    float4 gv = *(const float4*)(gamma + tid * 4);
    float4 bev = *(const float4*)(beta + tid * 4);
    float o0 = d0 * rs * gv.x + bev.x, o1 = d1 * rs * gv.y + bev.y;
    float o2 = d2 * rs * gv.z + bev.z, o3 = d3 * rs * gv.w + bev.w;
    *(float4*)(out + base) = make_float4(o0, o1, o2, o3);
    if (outb) {
        ushort4 ob;
        ob.x = f2b(o0); ob.y = f2b(o1); ob.z = f2b(o2); ob.w = f2b(o3);
        *(ushort4*)(outb + base) = ob;
    }
}

extern "C" void kernel_launch(void* const* d_in, const int* in_sizes, int n_in,
                              void* d_out, int out_size, void* d_ws, size_t ws_size,
                              hipStream_t stream) {
    const float* x    = (const float*)d_in[0];
    const float* adjm = (const float*)d_in[1];
    const float* comm = (const float*)d_in[2];
    const float* rel  = (const float*)d_in[3];
    const float* Wq   = (const float*)d_in[4];
    const float* bq   = (const float*)d_in[5];
    const float* Wk   = (const float*)d_in[6];
    const float* bk   = (const float*)d_in[7];
    const float* Wv   = (const float*)d_in[8];
    const float* bv   = (const float*)d_in[9];
    const float* Wo   = (const float*)d_in[10];
    const float* bo   = (const float*)d_in[11];
    const float* g1   = (const float*)d_in[12];
    const float* be1  = (const float*)d_in[13];
    const float* W1   = (const float*)d_in[14];
    const float* b1   = (const float*)d_in[15];
    const float* W2   = (const float*)d_in[16];
    const float* b2   = (const float*)d_in[17];
    const float* g2   = (const float*)d_in[18];
    const float* be2  = (const float*)d_in[19];
    float* out = (float*)d_out;

    char* ws = (char*)d_ws;
    const size_t MB = 1048576;
    u16*   xb    = (u16*)(ws + 0 * MB);      // 8 MiB (dead after gemm_qkv)
    u16*   Wqkvt = (u16*)(ws + 8 * MB);      // 6 MiB
    u16*   Wot   = (u16*)(ws + 14 * MB);     // 2 MiB
    u16*   W1t   = (u16*)(ws + 16 * MB);     // 8 MiB
    u16*   W2t   = (u16*)(ws + 24 * MB);     // 8 MiB (live through FFN2)
    u16*   Qab   = (u16*)(ws + 32 * MB);     // 8 MiB each [32,72)
    u16*   Qcb   = (u16*)(ws + 40 * MB);
    u16*   Kab   = (u16*)(ws + 48 * MB);
    u16*   Kcb   = (u16*)(ws + 56 * MB);
    u16*   Vtb   = (u16*)(ws + 64 * MB);
    float* ctxA  = (float*)(ws + 72 * MB);   // 16 MiB
    float* ctxC  = (float*)(ws + 88 * MB);   // 16 MiB
    u16*   ctx   = (u16*)(ws + 104 * MB);    // 8 MiB (dead after Wo gemm)
    float* ctxWo = (float*)(ws + 32 * MB);   // reuse Qab/Qcb (dead after attn)
    float* out1  = (float*)(ws + 48 * MB);   // reuse Kab/Kcb (live to LN2)
    u16*   out1b = (u16*)(ws + 64 * MB);     // reuse Vtb
    u16*   rb    = (u16*)(ws + 72 * MB);     // 32 MiB reuse ctxA/ctxC (dead after comb)
    float* ff2   = (float*)(ws + 0 * MB);    // 16 MiB reuse xb+weights (dead)

    dim3 tb(32, 8);
    // 1. casts / weight prep
    k_f2b<<<4096, 256, 0, stream>>>(x, xb, 1048576);
    k_wtrans<<<dim3(32, 32), tb, 0, stream>>>(Wq, Wqkvt, 1024, 1024);
    k_wtrans<<<dim3(32, 32), tb, 0, stream>>>(Wk, Wqkvt + 1024 * 1024, 1024, 1024);
    k_wtrans<<<dim3(32, 32), tb, 0, stream>>>(Wv, Wqkvt + 2 * 1024 * 1024, 1024, 1024);
    k_wtrans<<<dim3(32, 32), tb, 0, stream>>>(Wo, Wot, 1024, 1024);
    k_wtrans<<<dim3(128, 32), tb, 0, stream>>>(W1, W1t, 1024, 4096);
    k_wtrans<<<dim3(32, 128), tb, 0, stream>>>(W2, W2t, 4096, 1024);
    // 2. fused QKV projection + epilogues (Qa/Qc/Ka/Kc flat, Vt transposed)
    gemm_qkv<<<dim3(24, 32), 256, 0, stream>>>(xb, Wqkvt, bq, bk, bv, rel,
                                               Qab, Qcb, Kab, Kcb, Vtb);
    // 3. fused one-pass dual-mask attention (map on z) + combine
    k_attnf<<<dim3(1024, 1, 2), 256, 0, stream>>>(Qab, Qcb, Kab, Kcb, Vtb, adjm, comm, ctxA, ctxC);
    k_comb<<<4096, 256, 0, stream>>>(ctxA, ctxC, ctx, 1048576);
    // 4. output projection + LN1
    gemm_bt64<<<dim3(16, 32), 256, 0, stream>>>(ctx, Wot, ctxWo, 4096, 1024, 1024);
    k_ln<<<4096, 256, 0, stream>>>(ctxWo, bo, x, g1, be1, out1, out1b);
    // 5. FFN
    gemm_bt<1><<<dim3(32, 32), 256, 0, stream>>>(out1b, W1t, rb, 4096, 4096, 1024, b1);
    gemm_bt64<<<dim3(16, 32), 256, 0, stream>>>(rb, W2t, ff2, 4096, 1024, 4096);
    // 6. LN2 -> final output
    k_ln<<<4096, 256, 0, stream>>>(ff2, b2, out1, g2, be2, out, nullptr);
}